// Round 1
// baseline (127.374 us; speedup 1.0000x reference)
//
#include <hip/hip_runtime.h>
#include <hip/hip_fp16.h>
#include <stdint.h>

// ---------------------------------------------------------------------------
// ThreeBodyLayer fused kernel v7 (MI355X / gfx950)
//
// All-f16 MFMA pipeline, log2-domain softplus. Scale algebra: W1/b1 carry
// log2(e); W2 carries ln2*log2(e)=1; b2*log2(e); W3*ln2.
//
// v7 vs v6 (tb_fused 43.9us, dur_us 127, 2.1M LDS bank conflicts):
//  - ZERO workspace use: weight prep (W1 transpose->f16, W2 frags, scaled
//    biases) moved in-kernel. The harness's 256MiB ws re-poison fill
//    (~43us/iter of the 127us) should leave the timed stream; prep kernel
//    launch also removed. W1 (48KB) / W2 (8KB) are L2-resident broadcasts.
//  - XOR chunk swizzle on T and W1T (stride 1664 = 13*128, chunk^(row&7)):
//    phase-2 ds_read_b128 and phase-1 ds_write_b16 become bank-conflict-free
//    (v6: stride 1680 -> (ln+qd)%8 8-way groups; 72-half W1T rows -> same).
//  - LDS 77952 B (T 53248 + W1T 24576 + yred 128) -> 2 blocks/CU w/ slack.
//  - Phase-1 A-tile HBM loads issued before W1T staging to hide latency.
// ---------------------------------------------------------------------------

typedef __attribute__((ext_vector_type(8))) _Float16 f16x8;
typedef __attribute__((ext_vector_type(2))) __fp16   fp16v2;   // cvt_pkrtz ret
typedef __attribute__((ext_vector_type(4))) float    f32x4;
typedef __attribute__((ext_vector_type(4))) unsigned int u32x4;

constexpr int   BPB       = 32;       // batch elems per block
constexpr int   NT        = 1024;     // 16 waves
constexpr int   T_STRIDE  = 1664;     // 13 rows * 128 B, chunk-swizzled
constexpr int   WT_OFF    = BPB * T_STRIDE;       // 53248
constexpr int   Y_OFF     = WT_OFF + 192 * 128;   // 77824
constexpr int   LDS_BYTES = Y_OFF + 128;          // 77952 -> 2 blocks/CU

constexpr float L2E = 1.4426950408889634f;
constexpr float LN2 = 0.6931471805599453f;

// PAIRS i/j packed 3 bits per pair (15 pairs)
constexpr unsigned long long I_BITS =
  (0ull<<0)|(0ull<<3)|(0ull<<6)|(0ull<<9)|(0ull<<12)|
  (1ull<<15)|(1ull<<18)|(1ull<<21)|(1ull<<24)|
  (2ull<<27)|(2ull<<30)|(2ull<<33)|
  (3ull<<36)|(3ull<<39)|(4ull<<42);
constexpr unsigned long long J_BITS =
  (1ull<<0)|(2ull<<3)|(3ull<<6)|(4ull<<9)|(5ull<<12)|
  (2ull<<15)|(3ull<<18)|(4ull<<21)|(5ull<<24)|
  (3ull<<27)|(4ull<<30)|(5ull<<33)|
  (4ull<<36)|(5ull<<39)|(5ull<<42);

__device__ __forceinline__ float sp2(float s) {       // log2(1+exp2(s))
  float t = __builtin_amdgcn_exp2f(s);
  return __builtin_amdgcn_logf(1.0f + t);             // v_log_f32 = log2
}

__device__ __forceinline__ __half2 h1pair(__half2 u, __half2 a, __half2 b,
                                          __half2 one2) {
  __half2 s = __hadd2(__hadd2(u, a), b);
  __half2 t = h2exp2(s);                              // |s|<~8 -> safe in f16
  return h2log2(__hadd2(one2, t));
}

// ------------------------------ main kernel --------------------------------
__global__ __launch_bounds__(NT, 8)
void tb_fused(const float* __restrict__ core, const float* __restrict__ ligs,
              const float* __restrict__ W1,   const float* __restrict__ b1,
              const float* __restrict__ W2,   const float* __restrict__ b2,
              const float* __restrict__ W3,   const float* __restrict__ b3,
              float* __restrict__ out)
{
  extern __shared__ char smem[];
  const int tid  = (int)threadIdx.x;
  const int lane = tid & 63;
  const int ln   = lane & 15;        // fragment column
  const int qd   = lane >> 4;        // fragment quad
  const int swz  = ln & 7;           // XOR chunk swizzle key (= row&7 users)
  const int wv   = __builtin_amdgcn_readfirstlane(tid >> 6);  // 0..15
  const int b0   = (int)blockIdx.x * BPB;

  float* yred = (float*)(smem + Y_OFF);

  // ---- Phase-1 A-tile prefetch (cold HBM): issue before LDS staging ------
  const int xr = wv >> 1;
  const int mt = wv & 1;
  float4 fA[4];
  if (wv < 14) {
    const float* src = (xr == 0)
        ? (core + (size_t)(b0 + mt * 16 + ln) * 64)
        : (ligs + ((size_t)(b0 + mt * 16 + ln) * 6 + (size_t)(xr - 1)) * 64);
    #pragma unroll
    for (int ks = 0; ks < 2; ++ks) {
      fA[ks * 2 + 0] = *(const float4*)(src + ks * 32 + qd * 8);
      fA[ks * 2 + 1] = *(const float4*)(src + ks * 32 + qd * 8 + 4);
    }
  }

  // ---- stage W1T in-kernel: f32 [d=192][n=64] -> LDS f16, swizzled -------
  // row = slab*64+n (128 B), chunk' = (dl>>3) ^ (n&7). Each thread: 2 coalesced
  // scalar loads (same n, d0/d0+1) -> RNE f16 pair -> one b32 write (free).
  #pragma unroll
  for (int rep = 0; rep < 6; ++rep) {
    const int t  = tid + rep * NT;                    // 0..6143
    const int n  = t & 63;
    const int d0 = (t >> 6) << 1;                     // even, 0..190
    const float g0 = W1[(size_t)d0 * 64 + n] * L2E;
    const float g1 = W1[(size_t)(d0 + 1) * 64 + n] * L2E;
    const uint32_t pk = (uint32_t)__half_as_ushort(__float2half(g0))
                      | ((uint32_t)__half_as_ushort(__float2half(g1)) << 16);
    const int slab = d0 >> 6, dl = d0 & 63;
    *(uint32_t*)(smem + WT_OFF + (slab * 64 + n) * 128
                 + (((dl >> 3) ^ (n & 7)) << 4) + (dl & 7) * 2) = pk;
  }
  if (tid < BPB) yred[tid] = 0.0f;
  __syncthreads();                                    // barrier #1: W1T ready

  // ------------- Phase 1: 14 jobs = (xr 0..6) x (mt 0..1), 1 per wave -----
  if (wv < 14) {
    union AF { f16x8 v; fp16v2 p[4]; } Afr[2];
    #pragma unroll
    for (int ks = 0; ks < 2; ++ks) {
      Afr[ks].p[0] = __builtin_amdgcn_cvt_pkrtz(fA[ks*2].x, fA[ks*2].y);
      Afr[ks].p[1] = __builtin_amdgcn_cvt_pkrtz(fA[ks*2].z, fA[ks*2].w);
      Afr[ks].p[2] = __builtin_amdgcn_cvt_pkrtz(fA[ks*2+1].x, fA[ks*2+1].y);
      Afr[ks].p[3] = __builtin_amdgcn_cvt_pkrtz(fA[ks*2+1].z, fA[ks*2+1].w);
    }

    const int sl_lo = (xr == 0) ? 0 : 1;
    const int sl_hi = (xr == 0) ? 0 : 2;
    #pragma unroll 1
    for (int sl = sl_lo; sl <= sl_hi; ++sl) {
      const int trow = (xr == 0) ? 0 : ((sl == 1) ? xr : 6 + xr);
      #pragma unroll
      for (int nt = 0; nt < 4; ++nt) {
        f32x4 c = {0.f, 0.f, 0.f, 0.f};
        #pragma unroll
        for (int ks = 0; ks < 2; ++ks) {
          // row = sl*64+nt*16+ln (row&7 == swz), chunk = ks*4+qd
          const f16x8 Bf = *(const f16x8*)(smem + WT_OFF
              + (sl * 64 + nt * 16 + ln) * 128 + ((((ks << 2) + qd) ^ swz) << 4));
          c = __builtin_amdgcn_mfma_f32_16x16x32_f16(Afr[ks].v, Bf, c, 0, 0, 0);
        }
        const float bias = (trow == 0) ? b1[nt * 16 + ln] * L2E : 0.0f;
        #pragma unroll
        for (int reg = 0; reg < 4; ++reg) {
          const int b = mt * 16 + qd * 4 + reg;       // C row = batch-local b
          // half index k = nt*16+ln: chunk = 2nt+(ln>>3) ^ (b&7), byte (ln&7)*2
          *(uint16_t*)(smem + (size_t)b * T_STRIDE + trow * 128
              + ((((nt << 1) + (ln >> 3)) ^ (b & 7)) << 4) + (ln & 7) * 2) =
              __half_as_ushort(__float2half(c[reg] + bias));
        }
      }
    }
  }

  // W2 B-frags + epilogue consts, straight from global (8KB, L1/L2-hot) —
  // overlaps Phase-1 tail. RNE converts match v6's prep numerics.
  f16x8 W2f[2][2];
  #pragma unroll
  for (int nt = 0; nt < 2; ++nt) {
    #pragma unroll
    for (int ks = 0; ks < 2; ++ks) {
      union { f16x8 v; uint16_t u[8]; } w;
      #pragma unroll
      for (int j = 0; j < 8; ++j)
        w.u[j] = __half_as_ushort(__float2half(
            W2[(size_t)(ks * 32 + qd * 8 + j) * 32 + nt * 16 + ln]));
      W2f[nt][ks] = w.v;
    }
  }
  float b2v[2], w3v[2];
  #pragma unroll
  for (int nt = 0; nt < 2; ++nt) {
    b2v[nt] = b2[nt * 16 + ln] * L2E;
    w3v[nt] = W3[nt * 16 + ln] * LN2;
  }

  __syncthreads();                                    // barrier #2: T ready

  // ------------- Phase 2: 60 units (30 q x 2 mt) over 16 waves ------------
  const int mtw = wv & 1;
  const int qr  = wv >> 1;                            // 0..7
  const __half2 one2 = __float2half2_rn(1.0f);
  const char* Tb = smem + (size_t)(mtw * 16 + ln) * T_STRIDE;
  const int k0 = ((qd)     ^ swz) << 4;               // chunk qd   (ks=0)
  const int k1 = ((qd + 4) ^ swz) << 4;               // chunk qd+4 (ks=1)

  float yacc[4] = {0.f, 0.f, 0.f, 0.f};

  #pragma unroll 2
  for (int t3 = 0; t3 < 4; ++t3) {
    const int q = qr + 8 * t3;
    if (q >= 30) break;                               // wave-uniform
    const int p  = q >> 1;
    const int iv = (int)((I_BITS >> (3 * p)) & 7ull);
    const int jv = (int)((J_BITS >> (3 * p)) & 7ull);
    const int An = (q & 1) ? jv : iv;
    const int Bn = (q & 1) ? iv : jv;
    const char* TA = Tb + (1 + An) * 128;
    const char* TB = Tb + (7 + Bn) * 128;

    union U4 { u32x4 u; __half2 h[4]; };
    U4 du0, da0, db0, du1, da1, db1;
    du0.u = *(const u32x4*)(Tb + k0);
    da0.u = *(const u32x4*)(TA + k0);
    db0.u = *(const u32x4*)(TB + k0);
    du1.u = *(const u32x4*)(Tb + k1);
    da1.u = *(const u32x4*)(TA + k1);
    db1.u = *(const u32x4*)(TB + k1);

    union { f16x8 v; __half2 h[4]; } A0, A1;
    #pragma unroll
    for (int w = 0; w < 4; ++w) A0.h[w] = h1pair(du0.h[w], da0.h[w], db0.h[w], one2);
    #pragma unroll
    for (int w = 0; w < 4; ++w) A1.h[w] = h1pair(du1.h[w], da1.h[w], db1.h[w], one2);

    f32x4 c0 = {0.f, 0.f, 0.f, 0.f};
    f32x4 c1 = {0.f, 0.f, 0.f, 0.f};
    c0 = __builtin_amdgcn_mfma_f32_16x16x32_f16(A0.v, W2f[0][0], c0, 0, 0, 0);
    c0 = __builtin_amdgcn_mfma_f32_16x16x32_f16(A1.v, W2f[0][1], c0, 0, 0, 0);
    c1 = __builtin_amdgcn_mfma_f32_16x16x32_f16(A0.v, W2f[1][0], c1, 0, 0, 0);
    c1 = __builtin_amdgcn_mfma_f32_16x16x32_f16(A1.v, W2f[1][1], c1, 0, 0, 0);

    #pragma unroll
    for (int reg = 0; reg < 4; ++reg) {
      yacc[reg] += sp2(c0[reg] + b2v[0]) * w3v[0]
                 + sp2(c1[reg] + b2v[1]) * w3v[1];
    }
  }

  // reduce over the 16 fragment columns (ln) inside each quad group
  #pragma unroll
  for (int reg = 0; reg < 4; ++reg) {
    float v = yacc[reg];
    v += __shfl_xor(v, 1);
    v += __shfl_xor(v, 2);
    v += __shfl_xor(v, 4);
    v += __shfl_xor(v, 8);
    yacc[reg] = v;
  }
  if (ln == 0) {
    #pragma unroll
    for (int reg = 0; reg < 4; ++reg)
      atomicAdd(&yred[mtw * 16 + qd * 4 + reg], yacc[reg]);
  }
  __syncthreads();
  if (tid < BPB) out[b0 + tid] = 0.5f * yred[tid] + 15.0f * b3[0];
}

extern "C" void kernel_launch(void* const* d_in, const int* in_sizes, int n_in,
                              void* d_out, int out_size, void* d_ws, size_t ws_size,
                              hipStream_t stream) {
  (void)d_ws; (void)ws_size;                // v7: workspace intentionally unused
  const float* core = (const float*)d_in[0];
  const float* ligs = (const float*)d_in[1];
  const float* W1   = (const float*)d_in[2];
  const float* b1   = (const float*)d_in[3];
  const float* W2   = (const float*)d_in[4];
  const float* b2   = (const float*)d_in[5];
  const float* W3   = (const float*)d_in[6];
  const float* b3   = (const float*)d_in[7];
  float* out = (float*)d_out;

  const int B = in_sizes[0] / 64;           // 32768
  const int grid = B / BPB;                 // 1024

  (void)hipFuncSetAttribute((const void*)tb_fused,
                            hipFuncAttributeMaxDynamicSharedMemorySize, LDS_BYTES);
  tb_fused<<<dim3(grid), dim3(NT), LDS_BYTES, stream>>>(
      core, ligs, W1, b1, W2, b2, W3, b3, out);
}